// Round 4
// baseline (623.375 us; speedup 1.0000x reference)
//
#include <hip/hip_runtime.h>

#define NSL 8
#define DIN 384
#define DS 128
#define BATCH 32
#define NPOS 4096
#define LN_EPS 1e-5f
#define THRESH 0.9f
#define NCH 32          // feature chunks per batch (128 rows each)

// attn = 0.125 exactly (softmax of identical logits across slots);
// sum over N = 512.0 exactly; 512.0f + 1e-8f == 512.0f; 0.125/512 = 2^-12
#define ATTN_NORM_C 0.000244140625f

// ---------------- K1: streaming  Σ_rows rstd·(x−μ)  (per column) + attn fill ----------------
// 16-lane row groups: 4 rows per wave-iter, shuffle chains depth 4, float4 loads.
__global__ __launch_bounds__(256) void colsum_kernel(const float* __restrict__ feat,
                                                     float* __restrict__ G_part,   // [32][NCH][384]
                                                     float* __restrict__ out_attn) {
    __shared__ float S_lds[16][384];   // 24 KB
    int t = threadIdx.x, w = t >> 6, lane = t & 63;
    int group = lane >> 4, gl = lane & 15;
    int b = blockIdx.y, ch = blockIdx.x;
    int row0 = ch * 128 + w * 32 + group;
    const float4* fbase = (const float4*)(feat + ((size_t)b * NPOS + row0) * DIN);

    float4 acc[6];
#pragma unroll
    for (int s = 0; s < 6; s++) { acc[s].x = 0.f; acc[s].y = 0.f; acc[s].z = 0.f; acc[s].w = 0.f; }

    for (int j = 0; j < 8; j++) {
        const float4* rp = fbase + (size_t)j * 384;   // +4 rows = 4*96 float4
        float4 x[6];
#pragma unroll
        for (int s = 0; s < 6; s++) x[s] = rp[s * 16 + gl];
        float sm = 0.f, sq = 0.f;
#pragma unroll
        for (int s = 0; s < 6; s++) {
            sm += x[s].x + x[s].y + x[s].z + x[s].w;
            sq += x[s].x * x[s].x + x[s].y * x[s].y + x[s].z * x[s].z + x[s].w * x[s].w;
        }
#pragma unroll
        for (int m = 1; m < 16; m <<= 1) {
            sm += __shfl_xor(sm, m, 64);
            sq += __shfl_xor(sq, m, 64);
        }
        float mean = sm * (1.f / 384.f);
        float var = sq * (1.f / 384.f) - mean * mean;
        float rstd = rsqrtf(var + LN_EPS);
#pragma unroll
        for (int s = 0; s < 6; s++) {
            acc[s].x += (x[s].x - mean) * rstd;
            acc[s].y += (x[s].y - mean) * rstd;
            acc[s].z += (x[s].z - mean) * rstd;
            acc[s].w += (x[s].w - mean) * rstd;
        }
    }
    int gr = w * 4 + group;
#pragma unroll
    for (int s = 0; s < 6; s++)
        *(float4*)&S_lds[gr][s * 64 + gl * 4] = acc[s];
    __syncthreads();
    // fixed-order combine of the 16 partials -> block partial (deterministic)
    for (int q = t; q < 384; q += 256) {
        float v = 0.f;
#pragma unroll
        for (int r = 0; r < 16; r++) v += S_lds[r][q];
        G_part[((size_t)b * NCH + ch) * 384 + q] = v;
    }
    // attn output is exactly 0.125 everywhere
    int s8 = t >> 5, p = t & 31;
    size_t ao = ((size_t)(b * 8 + s8)) * NPOS + ch * 128;
    out_attn[ao + p] = 0.125f;
    out_attn[ao + 32 + p] = 0.125f;
    out_attn[ao + 64 + p] = 0.125f;
    out_attn[ao + 96 + p] = 0.125f;
}

// ---------------- K2: fold g/b + @Wv -> u; 3x (GRU + LN + MLP); merge outputs ----------------
__global__ __launch_bounds__(128) void slots_kernel(
    const float* __restrict__ G_part,
    const float* __restrict__ g_in, const float* __restrict__ b_in,
    const float* __restrict__ Wv,
    const float* __restrict__ slot_mu,
    const float* __restrict__ W_ih, const float* __restrict__ W_hh,
    const float* __restrict__ b_ih, const float* __restrict__ b_hh,
    const float* __restrict__ gm, const float* __restrict__ bm,
    const float* __restrict__ W1, const float* __restrict__ b1v,
    const float* __restrict__ W2, const float* __restrict__ b2v,
    float* __restrict__ out_merged, float* __restrict__ out_mm,
    float* __restrict__ out_raw)
{
    __shared__ float S_l[384], u_l[128], h_l[128], m_l[128], hid_l[256];
    __shared__ float red[4];
    int b = blockIdx.x, d = threadIdx.x;

    // colsum = g * Σ_ch partial + 4096 * b   (fixed chunk order -> deterministic)
#pragma unroll
    for (int i = 0; i < 3; i++) {
        int q = d + i * 128;
        float s = 0.f;
        for (int ch = 0; ch < NCH; ch++) s += G_part[((size_t)b * NCH + ch) * 384 + q];
        S_l[q] = g_in[q] * s + 4096.f * b_in[q];
    }
    __syncthreads();
    // u = attn_norm * (colsum @ Wv)
    float u = 0.f;
    for (int k = 0; k < 384; k++) u += S_l[k] * Wv[k * 128 + d];
    u *= ATTN_NORM_C;
    u_l[d] = u;
    float h = slot_mu[d];
    h_l[d] = h;
    __syncthreads();

    // gx = W_ih @ u + b_ih : iteration-invariant (u is fixed)
    float gx[3];
#pragma unroll
    for (int jg = 0; jg < 3; jg++) {
        int j = jg * 128 + d;
        const float* wi = W_ih + j * 128;
        float ax = b_ih[j];
        for (int k = 0; k < 128; k++) ax += u_l[k] * wi[k];
        gx[jg] = ax;
    }

    for (int it = 0; it < 3; it++) {
        float gh[3];
#pragma unroll
        for (int jg = 0; jg < 3; jg++) {
            int j = jg * 128 + d;
            const float* wh = W_hh + j * 128;
            float ah = b_hh[j];
            for (int k = 0; k < 128; k++) ah += h_l[k] * wh[k];
            gh[jg] = ah;
        }
        float r = 1.f / (1.f + expf(-(gx[0] + gh[0])));
        float z = 1.f / (1.f + expf(-(gx[1] + gh[1])));
        float nn = tanhf(gx[2] + r * gh[2]);
        float hn = (1.f - z) * nn + z * h;
        // LN(hn)
        float s = hn, sq = hn * hn;
#pragma unroll
        for (int m = 1; m < 64; m <<= 1) { s += __shfl_xor(s, m, 64); sq += __shfl_xor(sq, m, 64); }
        if ((d & 63) == 0) { red[(d >> 6) * 2] = s; red[(d >> 6) * 2 + 1] = sq; }
        __syncthreads();
        s = red[0] + red[2]; sq = red[1] + red[3];
        float mean = s * (1.f / 128.f), var = sq * (1.f / 128.f) - mean * mean;
        float rstd = rsqrtf(var + LN_EPS);
        m_l[d] = (hn - mean) * rstd * gm[d] + bm[d];
        __syncthreads();
        // MLP
#pragma unroll
        for (int jj = 0; jj < 2; jj++) {
            int j = jj * 128 + d;
            float a = b1v[j];
            for (int k = 0; k < 128; k++) a += m_l[k] * W1[k * 256 + j];
            hid_l[j] = a / (1.f + expf(-a));   // silu
        }
        __syncthreads();
        float o = hn + b2v[d];
        for (int k = 0; k < 256; k++) o += hid_l[k] * W2[k * 128 + d];
        h = o;
        __syncthreads();
        h_l[d] = h;
        __syncthreads();
    }

    // merge: all 8 slots identical; off-diag sim = cos(h,h)
    float s2 = h * h;
#pragma unroll
    for (int m = 1; m < 64; m <<= 1) s2 += __shfl_xor(s2, m, 64);
    if ((d & 63) == 0) red[d >> 6] = s2;
    __syncthreads();
    float ss = red[0] + red[1];
    float nrm = fmaxf(sqrtf(ss), 1e-12f);
    float simv = ss / (nrm * nrm);
    int allmerge = (simv > THRESH) ? 1 : 0;

#pragma unroll
    for (int sl = 0; sl < 8; sl++) {
        out_raw[((size_t)(b * 8 + sl)) * 128 + d] = h;
        float mv = (sl == 0) ? h : (allmerge ? 0.f : h);
        out_merged[((size_t)(b * 8 + sl)) * 128 + d] = mv;
    }
    if (d < 8) out_mm[b * 8 + d] = allmerge ? 0.f : (float)d;
}

extern "C" void kernel_launch(void* const* d_in, const int* in_sizes, int n_in,
                              void* d_out, int out_size, void* d_ws, size_t ws_size,
                              hipStream_t stream) {
    const float* feat    = (const float*)d_in[0];
    const float* ln_in_g = (const float*)d_in[1];
    const float* ln_in_b = (const float*)d_in[2];
    const float* Wv      = (const float*)d_in[4];
    const float* W_ih    = (const float*)d_in[8];
    const float* W_hh    = (const float*)d_in[9];
    const float* b_ih    = (const float*)d_in[10];
    const float* b_hh    = (const float*)d_in[11];
    const float* ln_m_g  = (const float*)d_in[12];
    const float* ln_m_b  = (const float*)d_in[13];
    const float* W1      = (const float*)d_in[14];
    const float* b1      = (const float*)d_in[15];
    const float* W2      = (const float*)d_in[16];
    const float* b2      = (const float*)d_in[17];
    const float* slot_mu = (const float*)d_in[18];

    float* out        = (float*)d_out;
    float* out_merged = out;                       // 32768
    float* out_attn   = out + 32768;               // 1048576
    float* out_mm     = out + 32768 + 1048576;     // 256
    float* out_raw    = out_mm + 256;              // 32768

    float* G_part = (float*)d_ws;                  // [32][NCH][384] = 1,572,864 B

    colsum_kernel<<<dim3(NCH, BATCH), 256, 0, stream>>>(feat, G_part, out_attn);
    slots_kernel<<<32, 128, 0, stream>>>(G_part, ln_in_g, ln_in_b, Wv, slot_mu,
                                         W_ih, W_hh, b_ih, b_hh, ln_m_g, ln_m_b,
                                         W1, b1, W2, b2,
                                         out_merged, out_mm, out_raw);
}

// Round 5
// 594.235 us; speedup vs baseline: 1.0490x; 1.0490x over previous
//
#include <hip/hip_runtime.h>

#define NSL 8
#define DIN 384
#define DS 128
#define BATCH 32
#define NPOS 4096
#define LN_EPS 1e-5f
#define THRESH 0.9f
#define NCH 32          // feature chunks per batch (128 rows each)

// attn = 0.125 exactly (softmax of identical logits across slots);
// sum over N = 512.0 exactly; 512.0f + 1e-8f == 512.0f; 0.125/512 = 2^-12
#define ATTN_NORM_C 0.000244140625f

// ---------------- P0: transpose W_ih / W_hh for coalesced column access ----------------
__global__ __launch_bounds__(256) void prep_kernel(const float* __restrict__ Wih,
                                                   const float* __restrict__ Whh,
                                                   float* __restrict__ WihT,
                                                   float* __restrict__ WhhT) {
    int idx = blockIdx.x * 256 + threadIdx.x;   // 384*128 = 49152
    if (idx < 49152) {
        int j = idx / 128, k = idx % 128;
        WihT[k * 384 + j] = Wih[idx];
        WhhT[k * 384 + j] = Whh[idx];
    }
}

// ---------------- K1: streaming  Σ_rows rstd·(x−μ)  (per column) + attn fill ----------------
// 16-lane row groups, float4 loads, explicit register double-buffer (prefetch j+1).
__global__ __launch_bounds__(256) void colsum_kernel(const float* __restrict__ feat,
                                                     float* __restrict__ G_part,   // [32][NCH][384]
                                                     float* __restrict__ out_attn) {
    __shared__ float S_lds[16][384];   // 24 KB
    int t = threadIdx.x, w = t >> 6, lane = t & 63;
    int group = lane >> 4, gl = lane & 15;
    int b = blockIdx.y, ch = blockIdx.x;
    int row0 = ch * 128 + w * 32 + group;
    const float4* fbase = (const float4*)(feat + ((size_t)b * NPOS + row0) * DIN);

    float4 acc[6];
#pragma unroll
    for (int s = 0; s < 6; s++) { acc[s].x = 0.f; acc[s].y = 0.f; acc[s].z = 0.f; acc[s].w = 0.f; }

    float4 xA[6], xB[6];
#pragma unroll
    for (int s = 0; s < 6; s++) xA[s] = fbase[s * 16 + gl];

#pragma unroll
    for (int j = 0; j < 8; j++) {
        // prefetch next 4-row group while this one reduces
        if (j < 7) {
            const float4* rp = fbase + (size_t)(j + 1) * 384;
#pragma unroll
            for (int s = 0; s < 6; s++) xB[s] = rp[s * 16 + gl];
        }
        float sm = 0.f, sq = 0.f;
#pragma unroll
        for (int s = 0; s < 6; s++) {
            sm += xA[s].x + xA[s].y + xA[s].z + xA[s].w;
            sq += xA[s].x * xA[s].x + xA[s].y * xA[s].y + xA[s].z * xA[s].z + xA[s].w * xA[s].w;
        }
#pragma unroll
        for (int m = 1; m < 16; m <<= 1) {
            sm += __shfl_xor(sm, m, 64);
            sq += __shfl_xor(sq, m, 64);
        }
        float mean = sm * (1.f / 384.f);
        float var = sq * (1.f / 384.f) - mean * mean;
        float rstd = rsqrtf(var + LN_EPS);
#pragma unroll
        for (int s = 0; s < 6; s++) {
            acc[s].x += (xA[s].x - mean) * rstd;
            acc[s].y += (xA[s].y - mean) * rstd;
            acc[s].z += (xA[s].z - mean) * rstd;
            acc[s].w += (xA[s].w - mean) * rstd;
        }
#pragma unroll
        for (int s = 0; s < 6; s++) xA[s] = xB[s];
    }
    int gr = w * 4 + group;
#pragma unroll
    for (int s = 0; s < 6; s++)
        *(float4*)&S_lds[gr][s * 64 + gl * 4] = acc[s];
    __syncthreads();
    // fixed-order combine of the 16 partials -> block partial (deterministic)
    for (int q = t; q < 384; q += 256) {
        float v = 0.f;
#pragma unroll
        for (int r = 0; r < 16; r++) v += S_lds[r][q];
        G_part[((size_t)b * NCH + ch) * 384 + q] = v;
    }
    // attn output is exactly 0.125 everywhere
    int s8 = t >> 5, p = t & 31;
    size_t ao = ((size_t)(b * 8 + s8)) * NPOS + ch * 128;
    out_attn[ao + p] = 0.125f;
    out_attn[ao + 32 + p] = 0.125f;
    out_attn[ao + 64 + p] = 0.125f;
    out_attn[ao + 96 + p] = 0.125f;
}

// ---------------- K2: fold g/b + @Wv -> u; 3x (GRU + LN + MLP); merge outputs ----------------
// 384 threads: one gate-output j per thread; all weight reads coalesced (transposed).
__global__ __launch_bounds__(384) void slots_kernel(
    const float* __restrict__ G_part,
    const float* __restrict__ g_in, const float* __restrict__ b_in,
    const float* __restrict__ Wv,
    const float* __restrict__ slot_mu,
    const float* __restrict__ WihT, const float* __restrict__ WhhT,
    const float* __restrict__ b_ih, const float* __restrict__ b_hh,
    const float* __restrict__ gm, const float* __restrict__ bm,
    const float* __restrict__ W1, const float* __restrict__ b1v,
    const float* __restrict__ W2, const float* __restrict__ b2v,
    float* __restrict__ out_merged, float* __restrict__ out_mm,
    float* __restrict__ out_raw)
{
    __shared__ float S_l[384], u_l[128], h_l[128], m_l[128], hid_l[256];
    __shared__ float gx_l[384], gh_l[384];
    __shared__ float red[4];
    int b = blockIdx.x, t = threadIdx.x;

    // colsum = g * Σ_ch partial + 4096 * b   (fixed chunk order -> deterministic)
    {
        float s = 0.f;
#pragma unroll
        for (int ch = 0; ch < NCH; ch++) s += G_part[((size_t)b * NCH + ch) * 384 + t];
        S_l[t] = g_in[t] * s + 4096.f * b_in[t];
    }
    __syncthreads();
    // u = attn_norm * (colsum @ Wv)  ;  h = slot_mu
    if (t < 128) {
        float u = 0.f;
#pragma unroll
        for (int k = 0; k < 384; k++) u += S_l[k] * Wv[k * 128 + t];
        u_l[t] = u * ATTN_NORM_C;
        h_l[t] = slot_mu[t];
    }
    __syncthreads();
    // gx = W_ih @ u + b_ih : iteration-invariant
    {
        float ax = b_ih[t];
#pragma unroll
        for (int k = 0; k < 128; k++) ax += u_l[k] * WihT[k * 384 + t];
        gx_l[t] = ax;
    }
    __syncthreads();

    float h = (t < 128) ? h_l[t] : 0.f;
    float hn = 0.f;
    for (int it = 0; it < 3; it++) {
        // gh = W_hh @ h + b_hh  (one j per thread, coalesced, fully unrolled)
        {
            float ah = b_hh[t];
#pragma unroll
            for (int k = 0; k < 128; k++) ah += h_l[k] * WhhT[k * 384 + t];
            gh_l[t] = ah;
        }
        __syncthreads();
        if (t < 128) {
            float r = 1.f / (1.f + expf(-(gx_l[t] + gh_l[t])));
            float z = 1.f / (1.f + expf(-(gx_l[128 + t] + gh_l[128 + t])));
            float nn = tanhf(gx_l[256 + t] + r * gh_l[256 + t]);
            hn = (1.f - z) * nn + z * h;
            float s = hn, sq = hn * hn;
#pragma unroll
            for (int m = 1; m < 64; m <<= 1) { s += __shfl_xor(s, m, 64); sq += __shfl_xor(sq, m, 64); }
            if ((t & 63) == 0) { red[(t >> 6) * 2] = s; red[(t >> 6) * 2 + 1] = sq; }
        }
        __syncthreads();
        if (t < 128) {
            float s = red[0] + red[2], sq = red[1] + red[3];
            float mean = s * (1.f / 128.f), var = sq * (1.f / 128.f) - mean * mean;
            float rstd = rsqrtf(var + LN_EPS);
            m_l[t] = (hn - mean) * rstd * gm[t] + bm[t];
        }
        __syncthreads();
        if (t < 256) {
            float a = b1v[t];
#pragma unroll
            for (int k = 0; k < 128; k++) a += m_l[k] * W1[k * 256 + t];
            hid_l[t] = a / (1.f + expf(-a));   // silu
        }
        __syncthreads();
        if (t < 128) {
            float o = hn + b2v[t];
#pragma unroll
            for (int k = 0; k < 256; k++) o += hid_l[k] * W2[k * 128 + t];
            h = o;
            h_l[t] = o;
        }
        __syncthreads();
    }

    // merge: all 8 slots identical; off-diag sim = cos(h,h)
    if (t < 128) {
        float s2 = h * h;
#pragma unroll
        for (int m = 1; m < 64; m <<= 1) s2 += __shfl_xor(s2, m, 64);
        if ((t & 63) == 0) red[t >> 6] = s2;
    }
    __syncthreads();
    if (t < 128) {
        float ss = red[0] + red[1];
        float nrm = fmaxf(sqrtf(ss), 1e-12f);
        float simv = ss / (nrm * nrm);
        int allmerge = (simv > THRESH) ? 1 : 0;
#pragma unroll
        for (int sl = 0; sl < 8; sl++) {
            out_raw[((size_t)(b * 8 + sl)) * 128 + t] = h;
            float mv = (sl == 0) ? h : (allmerge ? 0.f : h);
            out_merged[((size_t)(b * 8 + sl)) * 128 + t] = mv;
        }
        if (t < 8) out_mm[b * 8 + t] = allmerge ? 0.f : (float)t;
    }
}

extern "C" void kernel_launch(void* const* d_in, const int* in_sizes, int n_in,
                              void* d_out, int out_size, void* d_ws, size_t ws_size,
                              hipStream_t stream) {
    const float* feat    = (const float*)d_in[0];
    const float* ln_in_g = (const float*)d_in[1];
    const float* ln_in_b = (const float*)d_in[2];
    const float* Wv      = (const float*)d_in[4];
    const float* W_ih    = (const float*)d_in[8];
    const float* W_hh    = (const float*)d_in[9];
    const float* b_ih    = (const float*)d_in[10];
    const float* b_hh    = (const float*)d_in[11];
    const float* ln_m_g  = (const float*)d_in[12];
    const float* ln_m_b  = (const float*)d_in[13];
    const float* W1      = (const float*)d_in[14];
    const float* b1      = (const float*)d_in[15];
    const float* W2      = (const float*)d_in[16];
    const float* b2      = (const float*)d_in[17];
    const float* slot_mu = (const float*)d_in[18];

    float* out        = (float*)d_out;
    float* out_merged = out;                       // 32768
    float* out_attn   = out + 32768;               // 1048576
    float* out_mm     = out + 32768 + 1048576;     // 256
    float* out_raw    = out_mm + 256;              // 32768

    float* G_part = (float*)d_ws;                  // [32][NCH][384] = 1,572,864 B
    float* WihT   = G_part + 32 * NCH * 384;       // 196,608 B
    float* WhhT   = WihT + 49152;                  // 196,608 B

    prep_kernel<<<192, 256, 0, stream>>>(W_ih, W_hh, WihT, WhhT);
    colsum_kernel<<<dim3(NCH, BATCH), 256, 0, stream>>>(feat, G_part, out_attn);
    slots_kernel<<<32, 384, 0, stream>>>(G_part, ln_in_g, ln_in_b, Wv, slot_mu,
                                         WihT, WhhT, b_ih, b_hh, ln_m_g, ln_m_b,
                                         W1, b1, W2, b2,
                                         out_merged, out_mm, out_raw);
}

// Round 6
// 362.639 us; speedup vs baseline: 1.7190x; 1.6386x over previous
//
#include <hip/hip_runtime.h>

#define NSL 8
#define DIN 384
#define DS 128
#define BATCH 32
#define NPOS 4096
#define LN_EPS 1e-5f
#define THRESH 0.9f
#define NCH 32          // feature chunks per batch (128 rows each)

// attn = 0.125 exactly (softmax of identical logits across slots);
// sum over N = 512.0 exactly; 512.0f + 1e-8f == 512.0f; 0.125/512 = 2^-12
#define ATTN_NORM_C 0.000244140625f

// ---------------- P0: transpose Wv / W1 / W2 so output-threads stream rows ----------------
__global__ __launch_bounds__(256) void prep_kernel(const float* __restrict__ Wv,
                                                   const float* __restrict__ W1,
                                                   const float* __restrict__ W2,
                                                   float* __restrict__ WvT,    // [128][384]
                                                   float* __restrict__ W1T,    // [256][128]
                                                   float* __restrict__ W2T) {  // [128][256]
    int idx = blockIdx.x * 256 + threadIdx.x;
    if (idx < 49152) {            // WvT[j][k] = Wv[k][j]
        int j = idx / 384, k = idx % 384;
        WvT[idx] = Wv[k * 128 + j];
    }
    if (idx < 32768) {            // W1T[j][k] = W1[k][j]
        int j = idx / 128, k = idx % 128;
        W1T[idx] = W1[k * 256 + j];
    }
    if (idx < 32768) {            // W2T[j][k] = W2[k][j]
        int j = idx / 256, k = idx % 256;
        W2T[idx] = W2[k * 128 + j];
    }
}

// ---------------- K1: streaming  Σ_rows rstd·(x−μ)  (per column) + attn fill ----------------
// (unchanged from round 5 — isolate the slots_kernel experiment)
__global__ __launch_bounds__(256) void colsum_kernel(const float* __restrict__ feat,
                                                     float* __restrict__ G_part,   // [32][NCH][384]
                                                     float* __restrict__ out_attn) {
    __shared__ float S_lds[16][384];   // 24 KB
    int t = threadIdx.x, w = t >> 6, lane = t & 63;
    int group = lane >> 4, gl = lane & 15;
    int b = blockIdx.y, ch = blockIdx.x;
    int row0 = ch * 128 + w * 32 + group;
    const float4* fbase = (const float4*)(feat + ((size_t)b * NPOS + row0) * DIN);

    float4 acc[6];
#pragma unroll
    for (int s = 0; s < 6; s++) { acc[s].x = 0.f; acc[s].y = 0.f; acc[s].z = 0.f; acc[s].w = 0.f; }

    float4 xA[6], xB[6];
#pragma unroll
    for (int s = 0; s < 6; s++) xA[s] = fbase[s * 16 + gl];

#pragma unroll
    for (int j = 0; j < 8; j++) {
        if (j < 7) {
            const float4* rp = fbase + (size_t)(j + 1) * 384;
#pragma unroll
            for (int s = 0; s < 6; s++) xB[s] = rp[s * 16 + gl];
        }
        float sm = 0.f, sq = 0.f;
#pragma unroll
        for (int s = 0; s < 6; s++) {
            sm += xA[s].x + xA[s].y + xA[s].z + xA[s].w;
            sq += xA[s].x * xA[s].x + xA[s].y * xA[s].y + xA[s].z * xA[s].z + xA[s].w * xA[s].w;
        }
#pragma unroll
        for (int m = 1; m < 16; m <<= 1) {
            sm += __shfl_xor(sm, m, 64);
            sq += __shfl_xor(sq, m, 64);
        }
        float mean = sm * (1.f / 384.f);
        float var = sq * (1.f / 384.f) - mean * mean;
        float rstd = rsqrtf(var + LN_EPS);
#pragma unroll
        for (int s = 0; s < 6; s++) {
            acc[s].x += (xA[s].x - mean) * rstd;
            acc[s].y += (xA[s].y - mean) * rstd;
            acc[s].z += (xA[s].z - mean) * rstd;
            acc[s].w += (xA[s].w - mean) * rstd;
        }
#pragma unroll
        for (int s = 0; s < 6; s++) xA[s] = xB[s];
    }
    int gr = w * 4 + group;
#pragma unroll
    for (int s = 0; s < 6; s++)
        *(float4*)&S_lds[gr][s * 64 + gl * 4] = acc[s];
    __syncthreads();
    for (int q = t; q < 384; q += 256) {
        float v = 0.f;
#pragma unroll
        for (int r = 0; r < 16; r++) v += S_lds[r][q];
        G_part[((size_t)b * NCH + ch) * 384 + q] = v;
    }
    int s8 = t >> 5, p = t & 31;
    size_t ao = ((size_t)(b * 8 + s8)) * NPOS + ch * 128;
    out_attn[ao + p] = 0.125f;
    out_attn[ao + 32 + p] = 0.125f;
    out_attn[ao + 64 + p] = 0.125f;
    out_attn[ao + 96 + p] = 0.125f;
}

// ---------------- K2: batched-load matvecs; 3x (GRU + LN + MLP); merge outputs ----------------
// Every weight matvec streams a CONTIGUOUS row per thread in explicit batches of
// 16 float4 loads -> 16 loads in flight per round trip (was ~1 -> 290 us).
__global__ __launch_bounds__(384) void slots_kernel(
    const float* __restrict__ G_part,
    const float* __restrict__ g_in, const float* __restrict__ b_in,
    const float* __restrict__ WvT,
    const float* __restrict__ slot_mu,
    const float* __restrict__ W_ih, const float* __restrict__ W_hh,
    const float* __restrict__ b_ih, const float* __restrict__ b_hh,
    const float* __restrict__ gm, const float* __restrict__ bm,
    const float* __restrict__ W1T, const float* __restrict__ b1v,
    const float* __restrict__ W2T, const float* __restrict__ b2v,
    float* __restrict__ out_merged, float* __restrict__ out_mm,
    float* __restrict__ out_raw)
{
    __shared__ float S_l[384], u_l[128], h_l[128], m_l[128], hid_l[256];
    __shared__ float gx_l[384], gh_l[384];
    __shared__ float red[4];
    int b = blockIdx.x, t = threadIdx.x;

    // colsum = g * Σ_ch partial + 4096 * b   (32 independent loads, then fixed-order sum)
    {
        float r[NCH];
#pragma unroll
        for (int ch = 0; ch < NCH; ch++) r[ch] = G_part[((size_t)b * NCH + ch) * 384 + t];
        float s = 0.f;
#pragma unroll
        for (int ch = 0; ch < NCH; ch++) s += r[ch];
        S_l[t] = g_in[t] * s + 4096.f * b_in[t];
    }
    __syncthreads();

    // u = attn_norm * (colsum @ Wv)  — stream WvT row t (96 float4, batches of 16)
    if (t < 128) {
        const float4* wr = (const float4*)(WvT + t * 384);
        float u = 0.f;
#pragma unroll
        for (int kb = 0; kb < 96; kb += 16) {
            float4 w[16];
#pragma unroll
            for (int i = 0; i < 16; i++) w[i] = wr[kb + i];
#pragma unroll
            for (int i = 0; i < 16; i++) {
                int k = (kb + i) * 4;
                u += S_l[k] * w[i].x + S_l[k + 1] * w[i].y
                   + S_l[k + 2] * w[i].z + S_l[k + 3] * w[i].w;
            }
        }
        u_l[t] = u * ATTN_NORM_C;
        h_l[t] = slot_mu[t];
    }
    __syncthreads();

    // gx = W_ih @ u + b_ih  — W_ih row t is contiguous (original layout [384][128])
    {
        const float4* wr = (const float4*)(W_ih + t * 128);
        float ax = b_ih[t];
#pragma unroll
        for (int kb = 0; kb < 32; kb += 16) {
            float4 w[16];
#pragma unroll
            for (int i = 0; i < 16; i++) w[i] = wr[kb + i];
#pragma unroll
            for (int i = 0; i < 16; i++) {
                int k = (kb + i) * 4;
                ax += u_l[k] * w[i].x + u_l[k + 1] * w[i].y
                    + u_l[k + 2] * w[i].z + u_l[k + 3] * w[i].w;
            }
        }
        gx_l[t] = ax;
    }
    __syncthreads();

    float h = (t < 128) ? h_l[t] : 0.f;
    float hn = 0.f;
    for (int it = 0; it < 3; it++) {
        // gh = W_hh @ h + b_hh  — W_hh row t contiguous
        {
            const float4* wr = (const float4*)(W_hh + t * 128);
            float ah = b_hh[t];
#pragma unroll
            for (int kb = 0; kb < 32; kb += 16) {
                float4 w[16];
#pragma unroll
                for (int i = 0; i < 16; i++) w[i] = wr[kb + i];
#pragma unroll
                for (int i = 0; i < 16; i++) {
                    int k = (kb + i) * 4;
                    ah += h_l[k] * w[i].x + h_l[k + 1] * w[i].y
                        + h_l[k + 2] * w[i].z + h_l[k + 3] * w[i].w;
                }
            }
            gh_l[t] = ah;
        }
        __syncthreads();
        if (t < 128) {
            float r = 1.f / (1.f + expf(-(gx_l[t] + gh_l[t])));
            float z = 1.f / (1.f + expf(-(gx_l[128 + t] + gh_l[128 + t])));
            float nn = tanhf(gx_l[256 + t] + r * gh_l[256 + t]);
            hn = (1.f - z) * nn + z * h;
            float s = hn, sq = hn * hn;
#pragma unroll
            for (int m = 1; m < 64; m <<= 1) { s += __shfl_xor(s, m, 64); sq += __shfl_xor(sq, m, 64); }
            if ((t & 63) == 0) { red[(t >> 6) * 2] = s; red[(t >> 6) * 2 + 1] = sq; }
        }
        __syncthreads();
        if (t < 128) {
            float s = red[0] + red[2], sq = red[1] + red[3];
            float mean = s * (1.f / 128.f), var = sq * (1.f / 128.f) - mean * mean;
            float rstd = rsqrtf(var + LN_EPS);
            m_l[t] = (hn - mean) * rstd * gm[t] + bm[t];
        }
        __syncthreads();
        if (t < 256) {   // MLP layer 1 — stream W1T row t (32 float4)
            const float4* wr = (const float4*)(W1T + t * 128);
            float a = b1v[t];
#pragma unroll
            for (int kb = 0; kb < 32; kb += 16) {
                float4 w[16];
#pragma unroll
                for (int i = 0; i < 16; i++) w[i] = wr[kb + i];
#pragma unroll
                for (int i = 0; i < 16; i++) {
                    int k = (kb + i) * 4;
                    a += m_l[k] * w[i].x + m_l[k + 1] * w[i].y
                       + m_l[k + 2] * w[i].z + m_l[k + 3] * w[i].w;
                }
            }
            hid_l[t] = a / (1.f + expf(-a));   // silu
        }
        __syncthreads();
        if (t < 128) {   // MLP layer 2 — stream W2T row t (64 float4)
            const float4* wr = (const float4*)(W2T + t * 256);
            float o = hn + b2v[t];
#pragma unroll
            for (int kb = 0; kb < 64; kb += 16) {
                float4 w[16];
#pragma unroll
                for (int i = 0; i < 16; i++) w[i] = wr[kb + i];
#pragma unroll
                for (int i = 0; i < 16; i++) {
                    int k = (kb + i) * 4;
                    o += hid_l[k] * w[i].x + hid_l[k + 1] * w[i].y
                       + hid_l[k + 2] * w[i].z + hid_l[k + 3] * w[i].w;
                }
            }
            h = o;
            h_l[t] = o;
        }
        __syncthreads();
    }

    // merge: all 8 slots identical; off-diag sim = cos(h,h)
    if (t < 128) {
        float s2 = h * h;
#pragma unroll
        for (int m = 1; m < 64; m <<= 1) s2 += __shfl_xor(s2, m, 64);
        if ((t & 63) == 0) red[t >> 6] = s2;
    }
    __syncthreads();
    if (t < 128) {
        float ss = red[0] + red[1];
        float nrm = fmaxf(sqrtf(ss), 1e-12f);
        float simv = ss / (nrm * nrm);
        int allmerge = (simv > THRESH) ? 1 : 0;
#pragma unroll
        for (int sl = 0; sl < 8; sl++) {
            out_raw[((size_t)(b * 8 + sl)) * 128 + t] = h;
            float mv = (sl == 0) ? h : (allmerge ? 0.f : h);
            out_merged[((size_t)(b * 8 + sl)) * 128 + t] = mv;
        }
        if (t < 8) out_mm[b * 8 + t] = allmerge ? 0.f : (float)t;
    }
}

extern "C" void kernel_launch(void* const* d_in, const int* in_sizes, int n_in,
                              void* d_out, int out_size, void* d_ws, size_t ws_size,
                              hipStream_t stream) {
    const float* feat    = (const float*)d_in[0];
    const float* ln_in_g = (const float*)d_in[1];
    const float* ln_in_b = (const float*)d_in[2];
    const float* Wv      = (const float*)d_in[4];
    const float* W_ih    = (const float*)d_in[8];
    const float* W_hh    = (const float*)d_in[9];
    const float* b_ih    = (const float*)d_in[10];
    const float* b_hh    = (const float*)d_in[11];
    const float* ln_m_g  = (const float*)d_in[12];
    const float* ln_m_b  = (const float*)d_in[13];
    const float* W1      = (const float*)d_in[14];
    const float* b1      = (const float*)d_in[15];
    const float* W2      = (const float*)d_in[16];
    const float* b2      = (const float*)d_in[17];
    const float* slot_mu = (const float*)d_in[18];

    float* out        = (float*)d_out;
    float* out_merged = out;                       // 32768
    float* out_attn   = out + 32768;               // 1048576
    float* out_mm     = out + 32768 + 1048576;     // 256
    float* out_raw    = out_mm + 256;              // 32768

    float* G_part = (float*)d_ws;                  // [32][NCH][384] = 1,572,864 B
    float* WvT    = G_part + 32 * NCH * 384;       // [128][384] = 196,608 B
    float* W1T    = WvT + 49152;                   // [256][128] = 131,072 B
    float* W2T    = W1T + 32768;                   // [128][256] = 131,072 B

    prep_kernel<<<192, 256, 0, stream>>>(Wv, W1, W2, WvT, W1T, W2T);
    colsum_kernel<<<dim3(NCH, BATCH), 256, 0, stream>>>(feat, G_part, out_attn);
    slots_kernel<<<32, 384, 0, stream>>>(G_part, ln_in_g, ln_in_b, WvT, slot_mu,
                                         W_ih, W_hh, b_ih, b_hh, ln_m_g, ln_m_b,
                                         W1T, b1, W2T, b2,
                                         out_merged, out_mm, out_raw);
}